// Round 6
// baseline (359.264 us; speedup 1.0000x reference)
//
#include <hip/hip_runtime.h>
#include <math.h>
#include <stdint.h>

// Problem constants
#define N_B 4
#define N_H 16
#define L_Q 2048
#define L_K 2048
#define E_D 1024
#define DH  64
#define QB  128          // main kernel q-rows per block (8 waves x 16 rows)
#define KB  64
#define NT  512
#define NQT (L_Q / QB)   // 16
#define NKT (L_K / KB)   // 32
#define LDP  72          // padded stride (f16) for Ps
#define LDPV 68

typedef _Float16 f16x2 __attribute__((ext_vector_type(2)));
typedef _Float16 f16x4 __attribute__((ext_vector_type(4)));
typedef _Float16 f16x8 __attribute__((ext_vector_type(8)));
typedef float    f32x4 __attribute__((ext_vector_type(4)));

__device__ __forceinline__ f16x4 pk4(float a, float b, float c, float d) {
    f16x2 lo = __builtin_bit_cast(f16x2, __builtin_amdgcn_cvt_pkrtz(a, b));
    f16x2 hi = __builtin_bit_cast(f16x2, __builtin_amdgcn_cvt_pkrtz(c, d));
    f16x4 r; r[0] = lo[0]; r[1] = lo[1]; r[2] = hi[0]; r[3] = hi[1];
    return r;
}

__device__ __forceinline__ void gload16(const _Float16* g, _Float16* l) {
    __builtin_amdgcn_global_load_lds(
        (const __attribute__((address_space(1))) void*)g,
        (__attribute__((address_space(3))) void*)l, 16, 0, 0);
}

// ======================= prep kernels =======================
__global__ __launch_bounds__(256)
void cvt_qk(const float* __restrict__ Q, const float* __restrict__ K,
            _Float16* __restrict__ Qh, _Float16* __restrict__ Kh)
{
    size_t i = ((size_t)blockIdx.x * 256 + threadIdx.x) * 8;
    float4 a = *(const float4*)(Q + i);
    float4 b = *(const float4*)(Q + i + 4);
    *(f16x4*)(Qh + i)     = pk4(a.x, a.y, a.z, a.w);
    *(f16x4*)(Qh + i + 4) = pk4(b.x, b.y, b.z, b.w);
    float4 c = *(const float4*)(K + i);
    float4 d = *(const float4*)(K + i + 4);
    *(f16x4*)(Kh + i)     = pk4(c.x, c.y, c.z, c.w);
    *(f16x4*)(Kh + i + 4) = pk4(d.x, d.y, d.z, d.w);
}

__global__ __launch_bounds__(256)
void cvt_vt(const float* __restrict__ V, _Float16* __restrict__ Vt)
{
    __shared__ _Float16 T[64][72];
    const int bid = blockIdx.x;
    const int st  = bid & 31;
    const int nh  = bid >> 5;
    const int n   = nh >> 4;
    const int h   = nh & 15;
    const int t   = threadIdx.x;
    const float* Vb = V + ((size_t)(n * L_K + st * 64)) * E_D + h * DH;
    #pragma unroll
    for (int i = 0; i < 4; ++i) {
        int lin = t + i * 256;
        int s = lin >> 4, d = (lin & 15) * 4;
        float4 v = *(const float4*)(Vb + (size_t)s * E_D + d);
        T[d + 0][s] = (_Float16)v.x; T[d + 1][s] = (_Float16)v.y;
        T[d + 2][s] = (_Float16)v.z; T[d + 3][s] = (_Float16)v.w;
    }
    __syncthreads();
    _Float16* Ob = Vt + ((size_t)nh * DH) * L_K + st * 64;
    #pragma unroll
    for (int j = 0; j < 2; ++j) {
        int lin = t + j * 256;
        int d = lin >> 3, sc = (lin & 7) * 8;
        *(f16x8*)(Ob + (size_t)d * L_K + sc) = *(const f16x8*)&T[d][sc];
    }
}

// ======================= l-sum kernel (former pass A) =======================
// 2048 blocks x 256 threads, 16 KB LDS -> 8 blocks/CU; computes inv_l per q-row.
__global__ __launch_bounds__(256)
void lsum_kernel(const _Float16* __restrict__ Qh, const _Float16* __restrict__ Kh,
                 const int* __restrict__ causp, float* __restrict__ Linv)
{
    __shared__ __attribute__((aligned(16))) _Float16 KsL[2][64 * DH];  // 8 KB each

    const int tid  = threadIdx.x;
    const int lane = tid & 63;
    const int wid  = tid >> 6;           // 0..3
    const int bid0 = blockIdx.x;
    const int bid  = ((bid0 & 7) << 8) + (bid0 >> 3);   // XCD swizzle (2048 % 8 == 0)
    const int qt   = 31 - (bid & 31);    // longest blocks first
    const int nh   = bid >> 5;
    const int q0   = qt * 64;
    const int n    = nh >> 4;
    const int h    = nh & 15;
    const bool causal = (*causp) != 0;
    const float scale = 0.125f;

    const int lrow = lane & 15;
    const int g    = lane >> 4;
    const int rb   = wid * 16;
    const int rsub = g * 4;
    const int kt_end = causal ? (qt + 1) : NKT;

    // staging source (inverse-swizzled; same scheme as main kernel)
    const int srow = wid * 16 + (lane >> 3);
    const int scol = (((lane & 7) ^ ((lane >> 3) & 7)) << 3);
    const _Float16* Ksrc0 = Kh + ((size_t)(n * L_K) + srow) * E_D + h * DH + scol;

    const int swz = (lrow & 7) << 4;
    const int cb0 = ((g * 16) ^ swz) >> 1;
    const int cb1 = ((64 + g * 16) ^ swz) >> 1;

    const _Float16* Qrow = Qh + ((size_t)(n * L_Q + q0 + rb + lrow)) * E_D + h * DH;
    const f16x8 qf0 = *(const f16x8*)(Qrow + g * 8);
    const f16x8 qf1 = *(const f16x8*)(Qrow + 32 + g * 8);

    #define LS_STAGE(b, kt) { const _Float16* s_ = Ksrc0 + (size_t)(kt) * KB * E_D; \
        gload16(s_,           &KsL[b][(wid * 2 + 0) * 512]); \
        gload16(s_ + 8 * E_D, &KsL[b][(wid * 2 + 1) * 512]); }
    #define LS_FRAG(buf, tc, half) (*(const f16x8*)&(buf)[(size_t)((tc) * 16 + lrow) * 64 + ((half) ? cb1 : cb0)])

    float l_part = 0.0f;
    LS_STAGE(0, 0);
    __syncthreads();
    for (int kt = 0; kt < kt_end; ++kt) {
        const int cur = kt & 1;
        if (kt + 1 < kt_end) LS_STAGE(cur ^ 1, kt + 1);

        f32x4 acc[4] = {};
        #pragma unroll
        for (int tc = 0; tc < 4; ++tc) {
            acc[tc] = __builtin_amdgcn_mfma_f32_16x16x32_f16(LS_FRAG(KsL[cur], tc, 0), qf0, acc[tc], 0, 0, 0);
            acc[tc] = __builtin_amdgcn_mfma_f32_16x16x32_f16(LS_FRAG(KsL[cur], tc, 1), qf1, acc[tc], 0, 0, 0);
        }
        const bool dm = causal && (kt == qt);
        #pragma unroll
        for (int tc = 0; tc < 4; ++tc) {
            #pragma unroll
            for (int i = 0; i < 4; ++i) {
                float v = acc[tc][i] * scale;
                bool ok = !dm || (tc * 16 + rsub + i <= rb + lrow);
                l_part += ok ? __expf(v) : 0.0f;
            }
        }
        __syncthreads();
    }
    l_part += __shfl_xor(l_part, 16);
    l_part += __shfl_xor(l_part, 32);
    if (g == 0) Linv[(size_t)nh * L_Q + q0 + rb + lrow] = 1.0f / l_part;
    #undef LS_STAGE
    #undef LS_FRAG
}

// ======================= main kernel (former pass B only) =======================
__global__ __launch_bounds__(NT)
void mha_main(const _Float16* __restrict__ Qh, const _Float16* __restrict__ Kh,
              const _Float16* __restrict__ Vth, const float* __restrict__ Linv,
              const int* __restrict__ causp,
              float* __restrict__ Yg, float* __restrict__ Wg)
{
    __shared__ __attribute__((aligned(16))) _Float16 KsL[2][KB * DH];  // 8 KB each
    __shared__ __attribute__((aligned(16))) _Float16 VsL[2][DH * KB];  // 8 KB each
    __shared__ __attribute__((aligned(16))) _Float16 Ps[QB][LDP];

    const int tid  = threadIdx.x;
    const int lane = tid & 63;
    const int wid  = tid >> 6;            // 0..7
    const int bid0 = blockIdx.x;
    const int bid  = ((bid0 & 7) << 7) + (bid0 >> 3);   // XCD swizzle (1024 % 8 == 0)
    const int qt   = (NQT - 1) - (bid & (NQT - 1));     // longest blocks first
    const int nh   = bid >> 4;
    const int q0   = qt * QB;
    const int n    = nh >> 4;
    const int h    = nh & 15;
    const bool causal = (*causp) != 0;
    const float scale = 0.125f;

    const int lrow = lane & 15;
    const int g    = lane >> 4;
    const int rb   = wid * 16;
    const int rsub = g * 4;
    const int kt_end = causal ? (2 * qt + 2) : NKT;

    float*  Ybase = Yg + ((size_t)(n * L_Q + q0)) * E_D + h * DH;
    float*  Wbase = Wg + ((size_t)nh * L_Q + q0) * L_K;

    // per-lane inv_l values (computed by lsum_kernel)
    const float* Lrow = Linv + (size_t)nh * L_Q + q0;
    const float inv_l = Lrow[rb + lrow];
    float winv[4];
    #pragma unroll
    for (int j = 0; j < 4; ++j) winv[j] = Lrow[rb + (lane >> 4) + 4 * j];

    // staging sources (inverse-swizzled per-lane)
    const int srow = wid * 8 + (lane >> 3);
    const int scol = (((lane & 7) ^ ((lane >> 3) & 7)) << 3);
    const _Float16* Ksrc0 = Kh  + ((size_t)(n * L_K) + srow) * E_D + h * DH + scol;
    const _Float16* Vsrc0 = Vth + ((size_t)nh * DH + srow) * L_K + scol;

    const int swz = (lrow & 7) << 4;
    const int cb0 = ((g * 16) ^ swz) >> 1;
    const int cb1 = ((64 + g * 16) ^ swz) >> 1;

    const _Float16* Qrow = Qh + ((size_t)(n * L_Q + q0 + rb + lrow)) * E_D + h * DH;
    const f16x8 qf0 = *(const f16x8*)(Qrow + g * 8);
    const f16x8 qf1 = *(const f16x8*)(Qrow + 32 + g * 8);

    #define STAGE_K(b, kt) gload16(Ksrc0 + (size_t)(kt) * KB * E_D, &KsL[b][wid * 512])
    #define STAGE_V(b, kt) gload16(Vsrc0 + (size_t)(kt) * KB,       &VsL[b][wid * 512])
    #define FRAG(buf, tc, half) (*(const f16x8*)&(buf)[(size_t)((tc) * 16 + lrow) * 64 + ((half) ? cb1 : cb0)])

    f32x4 o[4] = {};
    STAGE_K(0, 0);
    STAGE_V(0, 0);
    __syncthreads();
    for (int kt = 0; kt < kt_end; ++kt) {
        const int cur = kt & 1;
        if (kt + 1 < kt_end) { STAGE_K(cur ^ 1, kt + 1); STAGE_V(cur ^ 1, kt + 1); }

        f32x4 acc[4] = {};
        #pragma unroll
        for (int tc = 0; tc < 4; ++tc) {
            acc[tc] = __builtin_amdgcn_mfma_f32_16x16x32_f16(FRAG(KsL[cur], tc, 0), qf0, acc[tc], 0, 0, 0);
            acc[tc] = __builtin_amdgcn_mfma_f32_16x16x32_f16(FRAG(KsL[cur], tc, 1), qf1, acc[tc], 0, 0, 0);
        }

        const bool dm = causal && (kt >= 2 * qt);
        const int krel = (kt - 2 * qt) * 64;
        #pragma unroll
        for (int tc = 0; tc < 4; ++tc) {
            float v, p0, p1, p2, p3;
            v = acc[tc][0] * scale;
            p0 = (!dm || (krel + tc * 16 + rsub + 0 <= rb + lrow)) ? __expf(v) : 0.0f;
            v = acc[tc][1] * scale;
            p1 = (!dm || (krel + tc * 16 + rsub + 1 <= rb + lrow)) ? __expf(v) : 0.0f;
            v = acc[tc][2] * scale;
            p2 = (!dm || (krel + tc * 16 + rsub + 2 <= rb + lrow)) ? __expf(v) : 0.0f;
            v = acc[tc][3] * scale;
            p3 = (!dm || (krel + tc * 16 + rsub + 3 <= rb + lrow)) ? __expf(v) : 0.0f;
            *(f16x4*)&Ps[rb + lrow][tc * 16 + rsub] = pk4(p0, p1, p2, p3);
        }
        // Ps rows rb..rb+15 written & read by this wave only: lgkmcnt orders it.

        f16x8 pf0 = *(const f16x8*)&Ps[rb + lrow][0 + g * 8];
        f16x8 pf1 = *(const f16x8*)&Ps[rb + lrow][32 + g * 8];
        #pragma unroll
        for (int tc = 0; tc < 4; ++tc) {
            o[tc] = __builtin_amdgcn_mfma_f32_16x16x32_f16(FRAG(VsL[cur], tc, 0), pf0, o[tc], 0, 0, 0);
            o[tc] = __builtin_amdgcn_mfma_f32_16x16x32_f16(FRAG(VsL[cur], tc, 1), pf1, o[tc], 0, 0, 0);
        }

        // coalesced W store: lanes 0-15 cover one row (256 B)
        {
            float* Wt = Wbase + (size_t)kt * KB;
            const int c0 = (lane & 15) * 4;
            #pragma unroll
            for (int j = 0; j < 4; ++j) {
                const int rl = rb + (lane >> 4) + 4 * j;
                f16x4 pv = *(const f16x4*)&Ps[rl][c0];
                const float s = winv[j];
                float4 wv = make_float4((float)pv[0] * s, (float)pv[1] * s,
                                        (float)pv[2] * s, (float)pv[3] * s);
                *(float4*)(Wt + (size_t)rl * L_K + c0) = wv;
            }
        }
        __syncthreads();
    }

    // ---- Y write ----
    #pragma unroll
    for (int tc = 0; tc < 4; ++tc) {
        float4 yv = make_float4(o[tc][0] * inv_l, o[tc][1] * inv_l,
                                o[tc][2] * inv_l, o[tc][3] * inv_l);
        *(float4*)(Ybase + (size_t)(rb + lrow) * E_D + tc * 16 + rsub) = yv;
    }

    // ---- zero-fill masked upper columns ----
    if (causal && kt_end < NKT) {
        const int c0 = kt_end * KB;
        const int rem4 = (L_K - c0) >> 2;
        const float4 z = make_float4(0.f, 0.f, 0.f, 0.f);
        for (int r = 0; r < QB; ++r) {
            float* row = Wbase + (size_t)r * L_K + c0;
            for (int c4 = tid; c4 < rem4; c4 += NT) {
                *(float4*)(row + c4 * 4) = z;
            }
        }
    }
    #undef STAGE_K
    #undef STAGE_V
    #undef FRAG
}

// ======================= fallback (round-3 proven kernel) =======================
__global__ __launch_bounds__(256)
void mha_fwd_fallback(const float* __restrict__ Qg, const float* __restrict__ Kg,
                      const float* __restrict__ Vg, const int* __restrict__ causp,
                      float* __restrict__ Yg, float* __restrict__ Wg)
{
    __shared__ __attribute__((aligned(16))) _Float16 Qs[64][LDP];
    __shared__ __attribute__((aligned(16))) _Float16 Ks[64][LDP];
    __shared__ __attribute__((aligned(16))) _Float16 Psf[64][LDP];
    __shared__ __attribute__((aligned(16))) _Float16 Vt[DH][LDPV];

    const int tid  = threadIdx.x;
    const int lane = tid & 63;
    const int wid  = tid >> 6;
    const int bid  = blockIdx.x;
    const int qt   = bid & 31;
    const int nh   = bid >> 5;
    const int q0   = qt * 64;
    const int n    = nh >> 4;
    const int h    = nh & 15;
    const bool causal = (*causp) != 0;
    const float scale = 0.125f;

    const float* Qbase = Qg + ((size_t)(n * L_Q + q0)) * E_D + h * DH;
    const float* Kbase = Kg + ((size_t)n * L_K) * E_D + h * DH;
    const float* Vbase = Vg + ((size_t)n * L_K) * E_D + h * DH;
    float*       Ybase = Yg + ((size_t)(n * L_Q + q0)) * E_D + h * DH;
    float*       Wbase = Wg + ((size_t)nh * L_Q + q0) * L_K;

    const int lrow = lane & 15;
    const int lk   = (lane >> 4) * 8;
    const int rb   = wid * 16;
    const int rsub = (lane >> 4) * 4;
    const int kt_end = causal ? (qt + 1) : NKT;

    #pragma unroll
    for (int i = 0; i < 4; ++i) {
        int lin = tid + i * 256;
        int r = lin >> 4;
        int c = (lin & 15) * 4;
        float4 qv = *(const float4*)(Qbase + (size_t)r * E_D + c);
        *(f16x4*)&Qs[r][c] = pk4(qv.x, qv.y, qv.z, qv.w);
    }
    __syncthreads();
    const f16x8 qf0 = *(const f16x8*)&Qs[rb + lrow][lk];
    const f16x8 qf1 = *(const f16x8*)&Qs[rb + lrow][32 + lk];

    float l_part = 0.0f;
    for (int kt = 0; kt < kt_end; ++kt) {
        const float* Kt = Kbase + (size_t)kt * KB * E_D;
        __syncthreads();
        #pragma unroll
        for (int i = 0; i < 4; ++i) {
            int lin = tid + i * 256;
            int r = lin >> 4;
            int c = (lin & 15) * 4;
            float4 kv = *(const float4*)(Kt + (size_t)r * E_D + c);
            *(f16x4*)&Ks[r][c] = pk4(kv.x, kv.y, kv.z, kv.w);
        }
        __syncthreads();
        f32x4 acc[4] = {};
        #pragma unroll
        for (int tc = 0; tc < 4; ++tc) {
            f16x8 a0 = *(const f16x8*)&Ks[tc * 16 + lrow][lk];
            f16x8 a1 = *(const f16x8*)&Ks[tc * 16 + lrow][32 + lk];
            acc[tc] = __builtin_amdgcn_mfma_f32_16x16x32_f16(a0, qf0, acc[tc], 0, 0, 0);
            acc[tc] = __builtin_amdgcn_mfma_f32_16x16x32_f16(a1, qf1, acc[tc], 0, 0, 0);
        }
        const bool dm = causal && (kt == qt);
        #pragma unroll
        for (int tc = 0; tc < 4; ++tc) {
            #pragma unroll
            for (int i = 0; i < 4; ++i) {
                float v = acc[tc][i] * scale;
                bool ok = !dm || (tc * 16 + rsub + i <= rb + lrow);
                l_part += ok ? __expf(v) : 0.0f;
            }
        }
    }
    l_part += __shfl_xor(l_part, 16);
    l_part += __shfl_xor(l_part, 32);
    const float inv_l = 1.0f / l_part;

    f32x4 o[4] = {};
    for (int kt = 0; kt < kt_end; ++kt) {
        const float* Kt  = Kbase + (size_t)kt * KB * E_D;
        const float* Vtg = Vbase + (size_t)kt * KB * E_D;
        __syncthreads();
        #pragma unroll
        for (int i = 0; i < 4; ++i) {
            int lin = tid + i * 256;
            int r = lin >> 4;
            int c = (lin & 15) * 4;
            float4 kv = *(const float4*)(Kt + (size_t)r * E_D + c);
            *(f16x4*)&Ks[r][c] = pk4(kv.x, kv.y, kv.z, kv.w);
            int d   = lin & 63;
            int kk0 = (lin >> 6) * 4;
            float v0 = Vtg[(size_t)(kk0 + 0) * E_D + d];
            float v1 = Vtg[(size_t)(kk0 + 1) * E_D + d];
            float v2 = Vtg[(size_t)(kk0 + 2) * E_D + d];
            float v3 = Vtg[(size_t)(kk0 + 3) * E_D + d];
            *(f16x4*)&Vt[d][kk0] = pk4(v0, v1, v2, v3);
        }
        __syncthreads();
        f32x4 acc[4] = {};
        #pragma unroll
        for (int tc = 0; tc < 4; ++tc) {
            f16x8 a0 = *(const f16x8*)&Ks[tc * 16 + lrow][lk];
            f16x8 a1 = *(const f16x8*)&Ks[tc * 16 + lrow][32 + lk];
            acc[tc] = __builtin_amdgcn_mfma_f32_16x16x32_f16(a0, qf0, acc[tc], 0, 0, 0);
            acc[tc] = __builtin_amdgcn_mfma_f32_16x16x32_f16(a1, qf1, acc[tc], 0, 0, 0);
        }
        const bool dm = causal && (kt == qt);
        float* Wrow = Wbase + (size_t)(rb + lrow) * L_K + kt * KB;
        #pragma unroll
        for (int tc = 0; tc < 4; ++tc) {
            float v, p0, p1, p2, p3;
            v = acc[tc][0] * scale;
            p0 = (!dm || (tc * 16 + rsub + 0 <= rb + lrow)) ? __expf(v) : 0.0f;
            v = acc[tc][1] * scale;
            p1 = (!dm || (tc * 16 + rsub + 1 <= rb + lrow)) ? __expf(v) : 0.0f;
            v = acc[tc][2] * scale;
            p2 = (!dm || (tc * 16 + rsub + 2 <= rb + lrow)) ? __expf(v) : 0.0f;
            v = acc[tc][3] * scale;
            p3 = (!dm || (tc * 16 + rsub + 3 <= rb + lrow)) ? __expf(v) : 0.0f;
            float4 wv = make_float4(p0 * inv_l, p1 * inv_l, p2 * inv_l, p3 * inv_l);
            *(float4*)(Wrow + tc * 16 + rsub) = wv;
            *(f16x4*)&Psf[rb + lrow][tc * 16 + rsub] = pk4(p0, p1, p2, p3);
        }
        f16x8 pf0 = *(const f16x8*)&Psf[rb + lrow][lk];
        f16x8 pf1 = *(const f16x8*)&Psf[rb + lrow][32 + lk];
        #pragma unroll
        for (int tc = 0; tc < 4; ++tc) {
            f16x4 t0 = *(const f16x4*)&Vt[tc * 16 + lrow][lk];
            f16x4 t1 = *(const f16x4*)&Vt[tc * 16 + lrow][lk + 4];
            f16x8 a0 = __builtin_shufflevector(t0, t1, 0, 1, 2, 3, 4, 5, 6, 7);
            f16x4 t2 = *(const f16x4*)&Vt[tc * 16 + lrow][32 + lk];
            f16x4 t3 = *(const f16x4*)&Vt[tc * 16 + lrow][32 + lk + 4];
            f16x8 a1 = __builtin_shufflevector(t2, t3, 0, 1, 2, 3, 4, 5, 6, 7);
            o[tc] = __builtin_amdgcn_mfma_f32_16x16x32_f16(a0, pf0, o[tc], 0, 0, 0);
            o[tc] = __builtin_amdgcn_mfma_f32_16x16x32_f16(a1, pf1, o[tc], 0, 0, 0);
        }
    }
    #pragma unroll
    for (int tc = 0; tc < 4; ++tc) {
        float4 yv = make_float4(o[tc][0] * inv_l, o[tc][1] * inv_l,
                                o[tc][2] * inv_l, o[tc][3] * inv_l);
        *(float4*)(Ybase + (size_t)(rb + lrow) * E_D + tc * 16 + rsub) = yv;
    }
    if (causal && kt_end < NKT) {
        const int c0 = kt_end * KB;
        const int rem4 = (L_K - c0) >> 2;
        const float4 z = make_float4(0.f, 0.f, 0.f, 0.f);
        for (int r = 0; r < 64; ++r) {
            float* row = Wbase + (size_t)r * L_K + c0;
            for (int c4 = tid; c4 < rem4; c4 += 256) {
                *(float4*)(row + c4 * 4) = z;
            }
        }
    }
}

extern "C" void kernel_launch(void* const* d_in, const int* in_sizes, int n_in,
                              void* d_out, int out_size, void* d_ws, size_t ws_size,
                              hipStream_t stream) {
    const float* Q  = (const float*)d_in[0];
    const float* K  = (const float*)d_in[1];
    const float* V  = (const float*)d_in[2];
    const int* caus = (const int*)d_in[3];
    float* Y = (float*)d_out;
    float* W = (float*)d_out + (size_t)N_B * L_Q * E_D;

    const size_t elems = (size_t)N_B * L_Q * E_D;         // 8.4M
    const size_t lsz   = (size_t)N_B * N_H * L_Q;         // 131072 rows
    const size_t need  = 3 * elems * sizeof(_Float16) + lsz * sizeof(float);

    if (ws_size >= need) {
        _Float16* Qh = (_Float16*)d_ws;
        _Float16* Kh = Qh + elems;
        _Float16* Vt = Kh + elems;
        float*  Linv = (float*)(Vt + elems);
        hipLaunchKernelGGL(cvt_qk, dim3(elems / (256 * 8)), dim3(256), 0, stream, Q, K, Qh, Kh);
        hipLaunchKernelGGL(cvt_vt, dim3(N_B * N_H * (L_K / 64)), dim3(256), 0, stream, V, Vt);
        hipLaunchKernelGGL(lsum_kernel, dim3(N_B * N_H * 32), dim3(256), 0, stream,
                           Qh, Kh, caus, Linv);
        hipLaunchKernelGGL(mha_main, dim3(N_B * N_H * NQT), dim3(NT), 0, stream,
                           Qh, Kh, Vt, Linv, caus, Y, W);
    } else {
        hipLaunchKernelGGL(mha_fwd_fallback, dim3(N_B * N_H * 32), dim3(256), 0, stream,
                           Q, K, V, caus, Y, W);
    }
}

// Round 7
// 352.226 us; speedup vs baseline: 1.0200x; 1.0200x over previous
//
#include <hip/hip_runtime.h>
#include <math.h>
#include <stdint.h>

// Problem constants
#define N_B 4
#define N_H 16
#define L_Q 2048
#define L_K 2048
#define E_D 1024
#define DH  64
#define QB  64           // q-rows per block (4 waves x 16 rows)
#define KB  64
#define NT  256
#define NQT (L_Q / QB)   // 32
#define NKT (L_K / KB)   // 32
#define LDP  72          // fallback padding

typedef _Float16 f16x2 __attribute__((ext_vector_type(2)));
typedef _Float16 f16x4 __attribute__((ext_vector_type(4)));
typedef _Float16 f16x8 __attribute__((ext_vector_type(8)));
typedef float    f32x4 __attribute__((ext_vector_type(4)));

__device__ __forceinline__ f16x4 pk4(float a, float b, float c, float d) {
    f16x2 lo = __builtin_bit_cast(f16x2, __builtin_amdgcn_cvt_pkrtz(a, b));
    f16x2 hi = __builtin_bit_cast(f16x2, __builtin_amdgcn_cvt_pkrtz(c, d));
    f16x4 r; r[0] = lo[0]; r[1] = lo[1]; r[2] = hi[0]; r[3] = hi[1];
    return r;
}

__device__ __forceinline__ void gload16(const _Float16* g, _Float16* l) {
    __builtin_amdgcn_global_load_lds(
        (const __attribute__((address_space(1))) void*)g,
        (__attribute__((address_space(3))) void*)l, 16, 0, 0);
}

// ======================= prep kernels =======================
__global__ __launch_bounds__(256)
void cvt_qk(const float* __restrict__ Q, const float* __restrict__ K,
            _Float16* __restrict__ Qh, _Float16* __restrict__ Kh)
{
    size_t i = ((size_t)blockIdx.x * 256 + threadIdx.x) * 8;
    float4 a = *(const float4*)(Q + i);
    float4 b = *(const float4*)(Q + i + 4);
    *(f16x4*)(Qh + i)     = pk4(a.x, a.y, a.z, a.w);
    *(f16x4*)(Qh + i + 4) = pk4(b.x, b.y, b.z, b.w);
    float4 c = *(const float4*)(K + i);
    float4 d = *(const float4*)(K + i + 4);
    *(f16x4*)(Kh + i)     = pk4(c.x, c.y, c.z, c.w);
    *(f16x4*)(Kh + i + 4) = pk4(d.x, d.y, d.z, d.w);
}

__global__ __launch_bounds__(256)
void cvt_vt(const float* __restrict__ V, _Float16* __restrict__ Vt)
{
    __shared__ _Float16 T[64][72];
    const int bid = blockIdx.x;
    const int st  = bid & 31;
    const int nh  = bid >> 5;
    const int n   = nh >> 4;
    const int h   = nh & 15;
    const int t   = threadIdx.x;
    const float* Vb = V + ((size_t)(n * L_K + st * 64)) * E_D + h * DH;
    #pragma unroll
    for (int i = 0; i < 4; ++i) {
        int lin = t + i * 256;
        int s = lin >> 4, d = (lin & 15) * 4;
        float4 v = *(const float4*)(Vb + (size_t)s * E_D + d);
        T[d + 0][s] = (_Float16)v.x; T[d + 1][s] = (_Float16)v.y;
        T[d + 2][s] = (_Float16)v.z; T[d + 3][s] = (_Float16)v.w;
    }
    __syncthreads();
    _Float16* Ob = Vt + ((size_t)nh * DH) * L_K + st * 64;
    #pragma unroll
    for (int j = 0; j < 2; ++j) {
        int lin = t + j * 256;
        int d = lin >> 3, sc = (lin & 7) * 8;
        *(f16x8*)(Ob + (size_t)d * L_K + sc) = *(const f16x8*)&T[d][sc];
    }
}

// ======================= fused main kernel =======================
// 2048 blocks x 256 threads (4 waves x 16 q-rows), 32 KB LDS -> 4 blocks/CU.
__global__ __launch_bounds__(NT, 4)
void mha_fused(const _Float16* __restrict__ Qh, const _Float16* __restrict__ Kh,
               const _Float16* __restrict__ Vth, const int* __restrict__ causp,
               float* __restrict__ Yg, float* __restrict__ Wg)
{
    __shared__ __attribute__((aligned(16))) _Float16 KsL[2][KB * DH];  // 8 KB each
    __shared__ __attribute__((aligned(16))) _Float16 VsL[2][DH * KB];  // 8 KB each

    const int tid  = threadIdx.x;
    const int lane = tid & 63;
    const int wid  = tid >> 6;            // 0..3
    const int bid0 = blockIdx.x;
    const int bid  = ((bid0 & 7) << 8) + (bid0 >> 3);   // XCD swizzle (2048 % 8 == 0)
    const int qt   = (NQT - 1) - (bid & (NQT - 1));     // longest causal blocks first
    const int nh   = bid >> 5;
    const int q0   = qt * QB;
    const int n    = nh >> 4;
    const int h    = nh & 15;
    const bool causal = (*causp) != 0;
    const float scale = 0.125f;           // 1/sqrt(64)

    const int lrow = lane & 15;           // q within band (C/D col; B-frag col)
    const int g    = lane >> 4;           // 0..3
    const int rb   = wid * 16;            // wave's q-band
    const int rsub = g * 4;
    const int kt_end = causal ? (qt + 1) : NKT;

    float*  Ybase = Yg + ((size_t)(n * L_Q + q0)) * E_D + h * DH;
    float*  Wbase = Wg + ((size_t)nh * L_Q + q0) * L_K;

    // staging sources (inverse-swizzled per-lane; swizzle = col ^ ((row&7)<<3) elems)
    const int srow = wid * 16 + (lane >> 3);              // +8 for second issue
    const int scol = (((lane & 7) ^ ((lane >> 3) & 7)) << 3);
    const _Float16* Ksrc = Kh  + ((size_t)(n * L_K) + srow) * E_D + h * DH + scol;
    const _Float16* Vsrc = Vth + ((size_t)nh * DH + srow) * L_K + scol;

    // swizzled fragment read offsets (QK path, f16x8)
    const int swz = (lrow & 7) << 4;                      // bytes
    const int cb0 = ((g * 16) ^ swz) >> 1;                // elements
    const int cb1 = ((64 + g * 16) ^ swz) >> 1;
    const int vswz = (lrow & 7) << 3;                     // elements (PV f16x4 reads)

    // Q fragments straight from global f16
    const _Float16* Qrow = Qh + ((size_t)(n * L_Q + q0 + rb + lrow)) * E_D + h * DH;
    const f16x8 qf0 = *(const f16x8*)(Qrow + g * 8);
    const f16x8 qf1 = *(const f16x8*)(Qrow + 32 + g * 8);

    #define STAGE_K(b, kt) { const _Float16* s_ = Ksrc + (size_t)(kt) * KB * E_D; \
        gload16(s_,           &KsL[b][(wid * 2 + 0) * 512]); \
        gload16(s_ + 8 * E_D, &KsL[b][(wid * 2 + 1) * 512]); }
    #define STAGE_V(b, kt) { const _Float16* s_ = Vsrc + (size_t)(kt) * KB; \
        gload16(s_,           &VsL[b][(wid * 2 + 0) * 512]); \
        gload16(s_ + 8 * L_K, &VsL[b][(wid * 2 + 1) * 512]); }
    #define FRAG(buf, tc, half) (*(const f16x8*)&(buf)[(size_t)((tc) * 16 + lrow) * 64 + ((half) ? cb1 : cb0)])

    // ================= PASS A: row sums (m == 0) =================
    float l_part = 0.0f;
    STAGE_K(0, 0);
    __syncthreads();
    for (int kt = 0; kt < kt_end; ++kt) {
        const int cur = kt & 1;
        if (kt + 1 < kt_end) STAGE_K(cur ^ 1, kt + 1);

        f32x4 acc[4] = {};
        #pragma unroll
        for (int tc = 0; tc < 4; ++tc) {
            acc[tc] = __builtin_amdgcn_mfma_f32_16x16x32_f16(FRAG(KsL[cur], tc, 0), qf0, acc[tc], 0, 0, 0);
            acc[tc] = __builtin_amdgcn_mfma_f32_16x16x32_f16(FRAG(KsL[cur], tc, 1), qf1, acc[tc], 0, 0, 0);
        }
        const bool dm = causal && (kt == qt);
        #pragma unroll
        for (int tc = 0; tc < 4; ++tc) {
            #pragma unroll
            for (int i = 0; i < 4; ++i) {
                float v = acc[tc][i] * scale;     // S[q=rb+lrow][k=tc*16+rsub+i]
                bool ok = !dm || (tc * 16 + rsub + i <= rb + lrow);
                l_part += ok ? __expf(v) : 0.0f;
            }
        }
        __syncthreads();   // drains vmcnt: prefetched buffer ready
    }
    l_part += __shfl_xor(l_part, 16);
    l_part += __shfl_xor(l_part, 32);
    const float inv_l = 1.0f / l_part;    // per-lane; lane owns row q=rb+lrow

    // ================= PASS B: W stores + PV from registers =================
    f32x4 o[4] = {};
    STAGE_K(0, 0);
    STAGE_V(0, 0);
    __syncthreads();
    for (int kt = 0; kt < kt_end; ++kt) {
        const int cur = kt & 1;
        if (kt + 1 < kt_end) { STAGE_K(cur ^ 1, kt + 1); STAGE_V(cur ^ 1, kt + 1); }

        f32x4 acc[4] = {};
        #pragma unroll
        for (int tc = 0; tc < 4; ++tc) {
            acc[tc] = __builtin_amdgcn_mfma_f32_16x16x32_f16(FRAG(KsL[cur], tc, 0), qf0, acc[tc], 0, 0, 0);
            acc[tc] = __builtin_amdgcn_mfma_f32_16x16x32_f16(FRAG(KsL[cur], tc, 1), qf1, acc[tc], 0, 0, 0);
        }

        const bool dm = causal && (kt == qt);
        float* Wt = Wbase + (size_t)(rb + lrow) * L_K + (size_t)kt * KB;
        f16x4 ph[4];
        #pragma unroll
        for (int tc = 0; tc < 4; ++tc) {
            float pv0, pv1, pv2, pv3;
            {
                float v;
                v = acc[tc][0] * scale;
                pv0 = (!dm || (tc * 16 + rsub + 0 <= rb + lrow)) ? __expf(v) : 0.0f;
                v = acc[tc][1] * scale;
                pv1 = (!dm || (tc * 16 + rsub + 1 <= rb + lrow)) ? __expf(v) : 0.0f;
                v = acc[tc][2] * scale;
                pv2 = (!dm || (tc * 16 + rsub + 2 <= rb + lrow)) ? __expf(v) : 0.0f;
                v = acc[tc][3] * scale;
                pv3 = (!dm || (tc * 16 + rsub + 3 <= rb + lrow)) ? __expf(v) : 0.0f;
            }
            ph[tc] = pk4(pv0, pv1, pv2, pv3);          // unnorm f16, k=tc*16+4g+{0..3}
            f32x4 wv = { pv0 * inv_l, pv1 * inv_l, pv2 * inv_l, pv3 * inv_l };
            __builtin_nontemporal_store(wv, (f32x4*)(Wt + tc * 16 + rsub));
        }

        // PV: o^T[d][q] += sum_k V^T[d][k] * P[k][q]; ph[tk] IS the B-frag for
        // v_mfma_f32_16x16x16_f16 (k = (lane>>4)*4 + e) — no exchange needed.
        #pragma unroll
        for (int td = 0; td < 4; ++td) {
            #pragma unroll
            for (int tk = 0; tk < 4; ++tk) {
                f16x4 va = *(const f16x4*)&VsL[cur][(size_t)(td * 16 + lrow) * 64
                                                   + ((tk * 16 + rsub) ^ vswz)];
                o[td] = __builtin_amdgcn_mfma_f32_16x16x16f16(va, ph[tk], o[td], 0, 0, 0);
            }
        }
        __syncthreads();   // drains vmcnt: prefetched buffers ready
    }

    // ---- Y write: lane owns row q=rb+lrow; o[td][i] = O^T[d=td*16+rsub+i][q] ----
    #pragma unroll
    for (int td = 0; td < 4; ++td) {
        f32x4 yv = { o[td][0] * inv_l, o[td][1] * inv_l,
                     o[td][2] * inv_l, o[td][3] * inv_l };
        __builtin_nontemporal_store(yv, (f32x4*)(Ybase + (size_t)(rb + lrow) * E_D + td * 16 + rsub));
    }

    // ---- zero-fill masked upper columns of attn ----
    if (causal && kt_end < NKT) {
        const int c0 = kt_end * KB;
        const int rem4 = (L_K - c0) >> 2;
        const f32x4 z = { 0.f, 0.f, 0.f, 0.f };
        for (int r = 0; r < QB; ++r) {
            float* row = Wbase + (size_t)r * L_K + c0;
            for (int c4 = tid; c4 < rem4; c4 += NT) {
                __builtin_nontemporal_store(z, (f32x4*)(row + c4 * 4));
            }
        }
    }
    #undef STAGE_K
    #undef STAGE_V
    #undef FRAG
}

// ======================= fallback (round-3 proven kernel) =======================
__global__ __launch_bounds__(256)
void mha_fwd_fallback(const float* __restrict__ Qg, const float* __restrict__ Kg,
                      const float* __restrict__ Vg, const int* __restrict__ causp,
                      float* __restrict__ Yg, float* __restrict__ Wg)
{
    __shared__ __attribute__((aligned(16))) _Float16 Qs[64][LDP];
    __shared__ __attribute__((aligned(16))) _Float16 Ks[64][LDP];
    __shared__ __attribute__((aligned(16))) _Float16 Psf[64][LDP];
    __shared__ __attribute__((aligned(16))) _Float16 Vt[DH][68];

    const int tid  = threadIdx.x;
    const int lane = tid & 63;
    const int wid  = tid >> 6;
    const int bid  = blockIdx.x;
    const int qt   = bid & 31;
    const int nh   = bid >> 5;
    const int q0   = qt * 64;
    const int n    = nh >> 4;
    const int h    = nh & 15;
    const bool causal = (*causp) != 0;
    const float scale = 0.125f;

    const float* Qbase = Qg + ((size_t)(n * L_Q + q0)) * E_D + h * DH;
    const float* Kbase = Kg + ((size_t)n * L_K) * E_D + h * DH;
    const float* Vbase = Vg + ((size_t)n * L_K) * E_D + h * DH;
    float*       Ybase = Yg + ((size_t)(n * L_Q + q0)) * E_D + h * DH;
    float*       Wbase = Wg + ((size_t)nh * L_Q + q0) * L_K;

    const int lrow = lane & 15;
    const int lk   = (lane >> 4) * 8;
    const int rb   = wid * 16;
    const int rsub = (lane >> 4) * 4;
    const int kt_end = causal ? (qt + 1) : NKT;

    #pragma unroll
    for (int i = 0; i < 4; ++i) {
        int lin = tid + i * 256;
        int r = lin >> 4;
        int c = (lin & 15) * 4;
        float4 qv = *(const float4*)(Qbase + (size_t)r * E_D + c);
        *(f16x4*)&Qs[r][c] = pk4(qv.x, qv.y, qv.z, qv.w);
    }
    __syncthreads();
    const f16x8 qf0 = *(const f16x8*)&Qs[rb + lrow][lk];
    const f16x8 qf1 = *(const f16x8*)&Qs[rb + lrow][32 + lk];

    float l_part = 0.0f;
    for (int kt = 0; kt < kt_end; ++kt) {
        const float* Kt = Kbase + (size_t)kt * KB * E_D;
        __syncthreads();
        #pragma unroll
        for (int i = 0; i < 4; ++i) {
            int lin = tid + i * 256;
            int r = lin >> 4;
            int c = (lin & 15) * 4;
            float4 kv = *(const float4*)(Kt + (size_t)r * E_D + c);
            *(f16x4*)&Ks[r][c] = pk4(kv.x, kv.y, kv.z, kv.w);
        }
        __syncthreads();
        f32x4 acc[4] = {};
        #pragma unroll
        for (int tc = 0; tc < 4; ++tc) {
            f16x8 a0 = *(const f16x8*)&Ks[tc * 16 + lrow][lk];
            f16x8 a1 = *(const f16x8*)&Ks[tc * 16 + lrow][32 + lk];
            acc[tc] = __builtin_amdgcn_mfma_f32_16x16x32_f16(a0, qf0, acc[tc], 0, 0, 0);
            acc[tc] = __builtin_amdgcn_mfma_f32_16x16x32_f16(a1, qf1, acc[tc], 0, 0, 0);
        }
        const bool dm = causal && (kt == qt);
        #pragma unroll
        for (int tc = 0; tc < 4; ++tc) {
            #pragma unroll
            for (int i = 0; i < 4; ++i) {
                float v = acc[tc][i] * scale;
                bool ok = !dm || (tc * 16 + rsub + i <= rb + lrow);
                l_part += ok ? __expf(v) : 0.0f;
            }
        }
    }
    l_part += __shfl_xor(l_part, 16);
    l_part += __shfl_xor(l_part, 32);
    const float inv_l = 1.0f / l_part;

    f32x4 o[4] = {};
    for (int kt = 0; kt < kt_end; ++kt) {
        const float* Kt  = Kbase + (size_t)kt * KB * E_D;
        const float* Vtg = Vbase + (size_t)kt * KB * E_D;
        __syncthreads();
        #pragma unroll
        for (int i = 0; i < 4; ++i) {
            int lin = tid + i * 256;
            int r = lin >> 4;
            int c = (lin & 15) * 4;
            float4 kv = *(const float4*)(Kt + (size_t)r * E_D + c);
            *(f16x4*)&Ks[r][c] = pk4(kv.x, kv.y, kv.z, kv.w);
            int d   = lin & 63;
            int kk0 = (lin >> 6) * 4;
            float v0 = Vtg[(size_t)(kk0 + 0) * E_D + d];
            float v1 = Vtg[(size_t)(kk0 + 1) * E_D + d];
            float v2 = Vtg[(size_t)(kk0 + 2) * E_D + d];
            float v3 = Vtg[(size_t)(kk0 + 3) * E_D + d];
            *(f16x4*)&Vt[d][kk0] = pk4(v0, v1, v2, v3);
        }
        __syncthreads();
        f32x4 acc[4] = {};
        #pragma unroll
        for (int tc = 0; tc < 4; ++tc) {
            f16x8 a0 = *(const f16x8*)&Ks[tc * 16 + lrow][lk];
            f16x8 a1 = *(const f16x8*)&Ks[tc * 16 + lrow][32 + lk];
            acc[tc] = __builtin_amdgcn_mfma_f32_16x16x32_f16(a0, qf0, acc[tc], 0, 0, 0);
            acc[tc] = __builtin_amdgcn_mfma_f32_16x16x32_f16(a1, qf1, acc[tc], 0, 0, 0);
        }
        const bool dm = causal && (kt == qt);
        float* Wrow = Wbase + (size_t)(rb + lrow) * L_K + kt * KB;
        #pragma unroll
        for (int tc = 0; tc < 4; ++tc) {
            float v, p0, p1, p2, p3;
            v = acc[tc][0] * scale;
            p0 = (!dm || (tc * 16 + rsub + 0 <= rb + lrow)) ? __expf(v) : 0.0f;
            v = acc[tc][1] * scale;
            p1 = (!dm || (tc * 16 + rsub + 1 <= rb + lrow)) ? __expf(v) : 0.0f;
            v = acc[tc][2] * scale;
            p2 = (!dm || (tc * 16 + rsub + 2 <= rb + lrow)) ? __expf(v) : 0.0f;
            v = acc[tc][3] * scale;
            p3 = (!dm || (tc * 16 + rsub + 3 <= rb + lrow)) ? __expf(v) : 0.0f;
            float4 wv = make_float4(p0 * inv_l, p1 * inv_l, p2 * inv_l, p3 * inv_l);
            *(float4*)(Wrow + tc * 16 + rsub) = wv;
            *(f16x4*)&Psf[rb + lrow][tc * 16 + rsub] = pk4(p0, p1, p2, p3);
        }
        f16x8 pf0 = *(const f16x8*)&Psf[rb + lrow][lk];
        f16x8 pf1 = *(const f16x8*)&Psf[rb + lrow][32 + lk];
        #pragma unroll
        for (int tc = 0; tc < 4; ++tc) {
            f16x4 t0 = *(const f16x4*)&Vt[tc * 16 + lrow][lk];
            f16x4 t1 = *(const f16x4*)&Vt[tc * 16 + lrow][lk + 4];
            f16x8 a0 = __builtin_shufflevector(t0, t1, 0, 1, 2, 3, 4, 5, 6, 7);
            f16x4 t2 = *(const f16x4*)&Vt[tc * 16 + lrow][32 + lk];
            f16x4 t3 = *(const f16x4*)&Vt[tc * 16 + lrow][32 + lk + 4];
            f16x8 a1 = __builtin_shufflevector(t2, t3, 0, 1, 2, 3, 4, 5, 6, 7);
            o[tc] = __builtin_amdgcn_mfma_f32_16x16x32_f16(a0, pf0, o[tc], 0, 0, 0);
            o[tc] = __builtin_amdgcn_mfma_f32_16x16x32_f16(a1, pf1, o[tc], 0, 0, 0);
        }
    }
    #pragma unroll
    for (int tc = 0; tc < 4; ++tc) {
        float4 yv = make_float4(o[tc][0] * inv_l, o[tc][1] * inv_l,
                                o[tc][2] * inv_l, o[tc][3] * inv_l);
        *(float4*)(Ybase + (size_t)(rb + lrow) * E_D + tc * 16 + rsub) = yv;
    }
    if (causal && kt_end < NKT) {
        const int c0 = kt_end * KB;
        const int rem4 = (L_K - c0) >> 2;
        const float4 z = make_float4(0.f, 0.f, 0.f, 0.f);
        for (int r = 0; r < 64; ++r) {
            float* row = Wbase + (size_t)r * L_K + c0;
            for (int c4 = tid; c4 < rem4; c4 += 256) {
                *(float4*)(row + c4 * 4) = z;
            }
        }
    }
}

extern "C" void kernel_launch(void* const* d_in, const int* in_sizes, int n_in,
                              void* d_out, int out_size, void* d_ws, size_t ws_size,
                              hipStream_t stream) {
    const float* Q  = (const float*)d_in[0];
    const float* K  = (const float*)d_in[1];
    const float* V  = (const float*)d_in[2];
    const int* caus = (const int*)d_in[3];
    float* Y = (float*)d_out;
    float* W = (float*)d_out + (size_t)N_B * L_Q * E_D;

    const size_t elems = (size_t)N_B * L_Q * E_D;        // 8.4M
    const size_t need  = 3 * elems * sizeof(_Float16);   // ~50 MB

    if (ws_size >= need) {
        _Float16* Qh = (_Float16*)d_ws;
        _Float16* Kh = Qh + elems;
        _Float16* Vt = Kh + elems;
        hipLaunchKernelGGL(cvt_qk, dim3(elems / (256 * 8)), dim3(256), 0, stream, Q, K, Qh, Kh);
        hipLaunchKernelGGL(cvt_vt, dim3(N_B * N_H * (L_K / 64)), dim3(256), 0, stream, V, Vt);
        hipLaunchKernelGGL(mha_fused, dim3(N_B * N_H * NQT), dim3(NT), 0, stream,
                           Qh, Kh, Vt, caus, Y, W);
    } else {
        hipLaunchKernelGGL(mha_fwd_fallback, dim3(N_B * N_H * 32), dim3(256), 0, stream,
                           Q, K, V, caus, Y, W);
    }
}